// Round 1
// baseline (105555.554 us; speedup 1.0000x reference)
//
#include <hip/hip_runtime.h>

#define HS   512
#define LNUM 4
#define TT   128
#define MMEM 2048
#define FFD  2048
#define NB   256
#define NT   512
#define INV512 (1.0f/512.0f)
#define QSCALE 0.08838834764831845f  // 1/sqrt(128)

// ---------------- workspace layout (float offsets) ----------------
constexpr size_t OFF_K     = 0;                                   // L*M*HS
constexpr size_t OFF_V     = OFF_K     + (size_t)LNUM*MMEM*HS;    // L*M*HS
constexpr size_t OFF_WCOMB = OFF_V     + (size_t)LNUM*MMEM*HS;    // L*HS*HS
constexpr size_t OFF_WQT   = OFF_WCOMB + (size_t)LNUM*HS*HS;      // L*HS*HS (Wq^T * g1 folded)
constexpr size_t OFF_W2T   = OFF_WQT   + (size_t)LNUM*HS*HS;      // L*FF*HS
constexpr size_t OFF_CSA   = OFF_W2T   + (size_t)LNUM*FFD*HS;     // L*HS
constexpr size_t OFF_SQ    = OFF_CSA   + (size_t)LNUM*HS;         // L*HS
constexpr size_t OFF_CBQ   = OFF_SQ    + (size_t)LNUM*HS;         // L*HS
constexpr size_t OFF_STATE = OFF_CBQ   + (size_t)LNUM*HS;
constexpr size_t OFF_H     = OFF_STATE;                           // 2*L*HS
constexpr size_t OFF_C     = OFF_H     + 2*LNUM*HS;               // 2*L*HS
constexpr size_t OFF_XING  = OFF_C     + 2*LNUM*HS;               // HS
constexpr size_t OFF_Z1    = OFF_XING  + HS;                      // HS
constexpr size_t OFF_Z02   = OFF_Z1    + HS;                      // 2*HS
constexpr size_t OFF_T1    = OFF_Z02   + 2*HS;                    // HS
constexpr size_t OFF_T2    = OFF_T1    + HS;                      // HS
constexpr size_t OFF_Y     = OFF_T2    + HS;                      // HS
constexpr size_t OFF_Y2    = OFF_Y     + HS;                      // HS
constexpr size_t OFF_CTX   = OFF_Y2    + HS;                      // HS
constexpr size_t OFF_DEN   = OFF_CTX   + HS;                      // 4
constexpr size_t OFF_S1    = OFF_DEN   + 4;                       // 2
constexpr size_t OFF_S2    = OFF_S1    + 2;                       // 2
constexpr size_t OFF_BAR   = OFF_S2    + 2;                       // 2 (unsigned cnt, gen)
constexpr size_t WS_TOTAL  = OFF_BAR   + 4;

__device__ __forceinline__ float wred(float v) {
#pragma unroll
  for (int m = 32; m; m >>= 1) v += __shfl_xor(v, m);
  return v;
}
__device__ __forceinline__ float sigm(float x) { return 1.0f/(1.0f+__expf(-x)); }

__device__ __forceinline__ void gridbar(unsigned* cnt, unsigned* gen) {
  __syncthreads();
  if (threadIdx.x == 0) {
    __threadfence();
    unsigned g = __hip_atomic_load(gen, __ATOMIC_RELAXED, __HIP_MEMORY_SCOPE_AGENT);
    unsigned a = __hip_atomic_fetch_add(cnt, 1u, __ATOMIC_ACQ_REL, __HIP_MEMORY_SCOPE_AGENT);
    if (a == gridDim.x - 1) {
      __hip_atomic_store(cnt, 0u, __ATOMIC_RELAXED, __HIP_MEMORY_SCOPE_AGENT);
      __hip_atomic_fetch_add(gen, 1u, __ATOMIC_ACQ_REL, __HIP_MEMORY_SCOPE_AGENT);
    } else {
      while (__hip_atomic_load(gen, __ATOMIC_ACQUIRE, __HIP_MEMORY_SCOPE_AGENT) == g) {
        __builtin_amdgcn_s_sleep(1);
      }
    }
    __threadfence();
  }
  __syncthreads();
}

// ---------------- precompute kernels ----------------

// C[l,m,f] = sum_e hist[m,l,e]*caWin[l,koff+f,e] + caBin[l,koff+f]   (K: koff=HS, V: koff=2*HS)
__global__ __launch_bounds__(256) void kv_gemm(
    const float* __restrict__ hist, const float* __restrict__ caWin,
    const float* __restrict__ caBin, float* __restrict__ out, int koff) {
  __shared__ float As[16][64];
  __shared__ float Bs[16][64];
  const int l = blockIdx.z, m0 = blockIdx.x*64, f0 = blockIdx.y*64;
  const int tid = threadIdx.x, tm = tid >> 4, tf = tid & 15;
  float acc[4][4] = {};
  for (int e0 = 0; e0 < HS; e0 += 16) {
#pragma unroll
    for (int it = 0; it < 4; ++it) {
      int idx = tid + it*256, k = idx & 15, mm = idx >> 4;
      As[k][mm] = hist[((size_t)(m0+mm)*LNUM + l)*HS + e0 + k];
      Bs[k][mm] = caWin[((size_t)l*(3*HS) + koff + f0 + mm)*HS + e0 + k];
    }
    __syncthreads();
#pragma unroll
    for (int k = 0; k < 16; ++k) {
      float a[4], b[4];
#pragma unroll
      for (int x = 0; x < 4; ++x) { a[x] = As[k][tm*4+x]; b[x] = Bs[k][tf*4+x]; }
#pragma unroll
      for (int x = 0; x < 4; ++x)
#pragma unroll
        for (int y = 0; y < 4; ++y) acc[x][y] += a[x]*b[y];
    }
    __syncthreads();
  }
#pragma unroll
  for (int x = 0; x < 4; ++x)
#pragma unroll
    for (int y = 0; y < 4; ++y) {
      int m = m0 + tm*4 + x, f = f0 + tf*4 + y;
      out[((size_t)l*MMEM + m)*HS + f] = acc[x][y] + caBin[l*(3*HS) + koff + f];
    }
}

// wcomb[l,f,j] = sum_e saWo[l,f,e] * saWin[l,2HS+e,j]
__global__ __launch_bounds__(256) void wcomb_gemm(
    const float* __restrict__ saWo, const float* __restrict__ saWin, float* __restrict__ wcomb) {
  __shared__ float As[16][64];
  __shared__ float Bs[16][64];
  const int l = blockIdx.z, f0 = blockIdx.x*64, j0 = blockIdx.y*64;
  const int tid = threadIdx.x, tm = tid >> 4, tf = tid & 15;
  float acc[4][4] = {};
  for (int e0 = 0; e0 < HS; e0 += 16) {
#pragma unroll
    for (int it = 0; it < 4; ++it) {
      int idx = tid + it*256;
      { int k = idx & 15, ff = idx >> 4;
        As[k][ff] = saWo[((size_t)l*HS + f0+ff)*HS + e0 + k]; }
      { int jj = idx & 63, k = idx >> 6;
        Bs[k][jj] = saWin[((size_t)l*(3*HS) + 2*HS + e0 + k)*HS + j0 + jj]; }
    }
    __syncthreads();
#pragma unroll
    for (int k = 0; k < 16; ++k) {
      float a[4], b[4];
#pragma unroll
      for (int x = 0; x < 4; ++x) { a[x] = As[k][tm*4+x]; b[x] = Bs[k][tf*4+x]; }
#pragma unroll
      for (int x = 0; x < 4; ++x)
#pragma unroll
        for (int y = 0; y < 4; ++y) acc[x][y] += a[x]*b[y];
    }
    __syncthreads();
  }
#pragma unroll
  for (int x = 0; x < 4; ++x)
#pragma unroll
    for (int y = 0; y < 4; ++y)
      wcomb[(size_t)l*HS*HS + (size_t)(f0+tm*4+x)*HS + (j0+tf*4+y)] = acc[x][y];
}

// out[l,e,f] = in[l*inLS + f*C + e] * (g ? g[l*gLS + e] : 1)
__global__ __launch_bounds__(256) void transpose_scale(
    const float* __restrict__ in, size_t inLS, int R, int C,
    const float* __restrict__ g, size_t gLS, float* __restrict__ out, size_t outLS) {
  __shared__ float tile[32][33];
  const int l = blockIdx.z, e0 = blockIdx.x*32, f0 = blockIdx.y*32;
  const int tx = threadIdx.x & 31, ty = threadIdx.x >> 5;  // ty 0..7
#pragma unroll
  for (int r = 0; r < 32; r += 8)
    tile[ty+r][tx] = in[(size_t)l*inLS + (size_t)(f0+ty+r)*C + e0 + tx];
  __syncthreads();
#pragma unroll
  for (int r = 0; r < 32; r += 8) {
    int e = e0 + ty + r, f = f0 + tx;
    float s = g ? g[(size_t)l*gLS + e] : 1.0f;
    out[(size_t)l*outLS + (size_t)e*R + f] = tile[tx][ty+r] * s;
  }
}

// csa[l,f] = sum_e saWo[l,f,e]*sa_bin[l,2HS+e] + sa_bo[l,f]
__global__ __launch_bounds__(256) void csa_kernel(
    const float* __restrict__ saWo, const float* __restrict__ sabin,
    const float* __restrict__ sabo, float* __restrict__ csa) {
  const int w = threadIdx.x >> 6, lane = threadIdx.x & 63;
  const int row = blockIdx.x*4 + w;
  const int l = row >> 9, f = row & 511;
  float acc = 0;
#pragma unroll
  for (int k = 0; k < 8; ++k) {
    int e = lane + 64*k;
    acc += saWo[((size_t)l*HS + f)*HS + e] * sabin[l*(3*HS) + 2*HS + e];
  }
  acc = wred(acc);
  if (lane == 0) csa[row] = acc + sabo[l*HS + f];
}

// sq[l,f] = sum_e Wq[f,e]*g1[e];  cbq[l,f] = sum_e Wq[f,e]*b1[e] + ca_bin[l,f]
__global__ __launch_bounds__(256) void sqcbq_kernel(
    const float* __restrict__ caWin, const float* __restrict__ caBin,
    const float* __restrict__ lnG, const float* __restrict__ lnB,
    float* __restrict__ sq, float* __restrict__ cbq) {
  const int w = threadIdx.x >> 6, lane = threadIdx.x & 63;
  const int row = blockIdx.x*4 + w;
  const int l = row >> 9, f = row & 511;
  float a1 = 0, a2 = 0;
#pragma unroll
  for (int k = 0; k < 8; ++k) {
    int e = lane + 64*k;
    float wv = caWin[((size_t)l*(3*HS) + f)*HS + e];
    a1 += wv * lnG[l*(3*HS) + e];
    a2 += wv * lnB[l*(3*HS) + e];
  }
  a1 = wred(a1); a2 = wred(a2);
  if (lane == 0) { sq[row] = a1; cbq[row] = a2 + caBin[l*(3*HS) + f]; }
}

// ---------------- main persistent sequential kernel ----------------

__device__ __forceinline__ void do_update(
    int ip, int parp, int j,
    const float* __restrict__ t2g, const float* __restrict__ s2g,
    const float* __restrict__ Y2g, const float* __restrict__ z02g,
    const float* __restrict__ cG,
    const float* __restrict__ lnG, const float* __restrict__ lnB,
    const float* __restrict__ ffB2,
    float* sh_red, int w, int lane, float& xn, float& cn) {
  float m2 = s2g[0]*INV512;
  float r2 = rsqrtf(s2g[1]*INV512 - m2*m2 + 1e-5f);
  float x2 = (t2g[j]-m2)*r2*lnG[(ip*3+1)*HS+j] + lnB[(ip*3+1)*HS+j];
  float t3 = x2 + Y2g[j] + ffB2[ip*HS + j];
  float s_ = t3, q_ = t3*t3;
#pragma unroll
  for (int m = 32; m; m >>= 1) { s_ += __shfl_xor(s_, m); q_ += __shfl_xor(q_, m); }
  if (lane == 0) { sh_red[w] = s_; sh_red[8+w] = q_; }
  __syncthreads();
  if (threadIdx.x == 0) {
    float a = 0, b = 0;
#pragma unroll
    for (int k = 0; k < 8; ++k) { a += sh_red[k]; b += sh_red[8+k]; }
    sh_red[0] = a; sh_red[1] = b;
  }
  __syncthreads();
  float m3 = sh_red[0]*INV512;
  float r3 = rsqrtf(sh_red[1]*INV512 - m3*m3 + 1e-5f);
  float d  = (t3-m3)*r3*lnG[(ip*3+2)*HS+j] + lnB[(ip*3+2)*HS+j];
  float cp = cG[(parp*LNUM + ip)*HS + j];
  float ft = sigm(cp - d);
  float it = sigm(z02g[j]);
  float gt = tanhf(z02g[HS + j]);
  cn = ft*cp + it*gt;
  xn = tanhf(cn);
}

__global__ __launch_bounds__(NT, 2) void seq_kernel(
    const float* __restrict__ x,
    const float* __restrict__ Wx,  const float* __restrict__ bx,
    const float* __restrict__ Wh,  const float* __restrict__ bh,
    const float* __restrict__ caWo, const float* __restrict__ caBo,
    const float* __restrict__ ffW1, const float* __restrict__ ffB1,
    const float* __restrict__ ffB2,
    const float* __restrict__ lnG,  const float* __restrict__ lnB,
    float* __restrict__ ws, float* __restrict__ out) {
  float* Kb    = ws + OFF_K;
  float* Vb    = ws + OFF_V;
  float* Wcomb = ws + OFF_WCOMB;
  float* WqT   = ws + OFF_WQT;
  float* W2T   = ws + OFF_W2T;
  float* csag  = ws + OFF_CSA;
  float* sqg   = ws + OFF_SQ;
  float* cbqg  = ws + OFF_CBQ;
  float* hG    = ws + OFF_H;
  float* cG    = ws + OFF_C;
  float* xing  = ws + OFF_XING;
  float* z1g   = ws + OFF_Z1;
  float* z02g  = ws + OFF_Z02;
  float* t1g   = ws + OFF_T1;
  float* t2g   = ws + OFF_T2;
  float* Yg    = ws + OFF_Y;
  float* Y2g   = ws + OFF_Y2;
  float* ctxg  = ws + OFF_CTX;
  float* deng  = ws + OFF_DEN;
  float* s1g   = ws + OFF_S1;
  float* s2g   = ws + OFF_S2;
  unsigned* bcnt = (unsigned*)(ws + OFF_BAR);
  unsigned* bgen = bcnt + 1;

  __shared__ float sh_xin[HS], sh_h[HS], sh_vec[HS], sh_aux[HS];
  __shared__ float sh_q[128], sh_p[32], sh_red[16];

  const int bid = blockIdx.x, tid = threadIdx.x;
  const int w = tid >> 6, lane = tid & 63;

  for (int s = 0; s < TT*LNUM; ++s) {
    const int t = s >> 2, i = s & 3;
    const int par = t & 1;
    // ---------- H1: update(prev) fused + z gate-1 matvec + accumulator zeroing ----------
    {
      const int ip = (s-1) & 3, tp = (s-1) >> 2, parp = tp & 1;
      const bool upd = (s > 0) && (bid == 0 || (i > 0 && bid < 64));
      float xn = 0.f, cn = 0.f;
      if (upd) {
        do_update(ip, parp, tid, t2g, s2g, Y2g, z02g, cG, lnG, lnB, ffB2, sh_red, w, lane, xn, cn);
        if (bid == 0) {
          hG[((parp^1)*LNUM + ip)*HS + tid] = xn;
          cG[((parp^1)*LNUM + ip)*HS + tid] = cn;
          if (ip == 3) out[tp*HS + tid] = xn;
        }
      }
      if (bid < 64) {
        float xv = (i == 0) ? x[t*HS + tid] : xn;
        sh_xin[tid] = xv;
        sh_h[tid]   = hG[(par*LNUM + i)*HS + tid];
        if (bid == 0) xing[tid] = xv;
      } else if (bid == 64) { Yg[tid] = 0.f; }
      else if (bid == 65)   { ctxg[tid] = 0.f; }
      else if (bid == 66)   { if (tid < 4) deng[tid] = 0.f; else if (tid == 4) s1g[0] = 0.f; else if (tid == 5) s1g[1] = 0.f; }
      __syncthreads();
      if (bid < 64) {
        const int f = bid*8 + w;
        const float* wxr = Wx + (((size_t)i*3 + 1)*HS + f)*HS;
        const float* whr = Wh + (((size_t)i*3 + 1)*HS + f)*HS;
        float acc = 0;
#pragma unroll
        for (int k = 0; k < 8; ++k) {
          int e = lane + 64*k;
          acc += wxr[e]*sh_xin[e] + whr[e]*sh_h[e];
        }
        acc = wred(acc);
        if (lane == 0) z1g[f] = acc + bx[(i*3+1)*HS + f] + bh[(i*3+1)*HS + f];
      }
    }
    gridbar(bcnt, bgen);
    // ---------- H2: t1 = f0 + Wcomb@f0 + csa; deferred q accumulation; stats1 ----------
    if (bid < 32) {
      sh_vec[tid] = sigm(z1g[tid]);  // f0
      __syncthreads();
      const int j0 = bid*16;
#pragma unroll
      for (int rr = 0; rr < 2; ++rr) {
        const int r = w + rr*8, j = j0 + r;
        const float* wr = Wcomb + ((size_t)i*HS + j)*HS;
        float acc = 0;
#pragma unroll
        for (int k = 0; k < 8; ++k) { int e = lane + 64*k; acc += wr[e]*sh_vec[e]; }
        acc = wred(acc);
        if (lane == 0) {
          float t1v = sh_vec[j] + acc + csag[i*HS + j];
          t1g[j] = t1v;
          sh_aux[r] = t1v;
        }
      }
      __syncthreads();
      {
        float yl = 0;
#pragma unroll
        for (int r = 0; r < 16; ++r)
          yl += sh_aux[r] * WqT[((size_t)i*HS + j0 + r)*HS + tid];
        atomicAdd(&Yg[tid], yl);
      }
      if (w == 0 && lane < 16) {
        float v = sh_aux[lane], s_ = v, q_ = v*v;
#pragma unroll
        for (int m = 8; m; m >>= 1) { s_ += __shfl_xor(s_, m); q_ += __shfl_xor(q_, m); }
        if (lane == 0) { atomicAdd(&s1g[0], s_); atomicAdd(&s1g[1], q_); }
      }
    } else if (bid == 32) {
      Y2g[tid] = 0.f;
      if (tid == 0) s2g[0] = 0.f;
      if (tid == 1) s2g[1] = 0.f;
    }
    gridbar(bcnt, bgen);
    // ---------- H3: attention (scores+exp+ctx+den) + z gates 0,2 ----------
    {
      const int h = bid >> 6, mb = (bid & 63)*32;
      sh_xin[tid] = xing[tid];
      sh_h[tid]   = hG[(par*LNUM + i)*HS + tid];
      if (tid < 128) {
        float m1 = s1g[0]*INV512;
        float r1 = rsqrtf(s1g[1]*INV512 - m1*m1 + 1e-5f);
        int f = h*128 + tid;
        sh_q[tid] = r1*(Yg[f] - m1*sqg[i*HS + f]) + cbqg[i*HS + f];
      }
      __syncthreads();
#pragma unroll
      for (int c = 0; c < 4; ++c) {
        const int m_ = mb + w*4 + c;
        const float* kr = Kb + ((size_t)i*MMEM + m_)*HS + h*128;
        float acc = sh_q[lane]*kr[lane] + sh_q[lane+64]*kr[lane+64];
        acc = wred(acc);
        if (lane == 0) sh_p[w*4 + c] = __expf(acc * QSCALE);
      }
      __syncthreads();
      if (w < 2) {
        const int d = tid;  // 0..127
        float acc = 0;
#pragma unroll 8
        for (int ml = 0; ml < 32; ++ml)
          acc += sh_p[ml] * Vb[((size_t)i*MMEM + mb + ml)*HS + h*128 + d];
        atomicAdd(&ctxg[h*128 + d], acc);
      } else if (w == 2) {
        if (lane < 32) {
          float s_ = sh_p[lane];
#pragma unroll
          for (int m = 16; m; m >>= 1) s_ += __shfl_xor(s_, m);
          if (lane == 0) atomicAdd(&deng[h], s_);
        }
      } else if (w >= 4) {
        const int rowid = bid*4 + (w - 4);
        const int g = (rowid < 512) ? 0 : 2;
        const int f = rowid & 511;
        const float* wxr = Wx + (((size_t)i*3 + g)*HS + f)*HS;
        const float* whr = Wh + (((size_t)i*3 + g)*HS + f)*HS;
        float acc = 0;
#pragma unroll
        for (int k = 0; k < 8; ++k) {
          int e = lane + 64*k;
          acc += wxr[e]*sh_xin[e] + whr[e]*sh_h[e];
        }
        acc = wred(acc);
        if (lane == 0) z02g[(g ? HS : 0) + f] = acc + bx[(i*3+g)*HS + f] + bh[(i*3+g)*HS + f];
      }
    }
    gridbar(bcnt, bgen);
    // ---------- H4: t2 = x1 + caWo@(ctx/den) + bo; stats2 ----------
    if (bid < 32) {
      sh_vec[tid] = ctxg[tid] / deng[tid >> 7];
      __syncthreads();
      const float m1 = s1g[0]*INV512;
      const float r1 = rsqrtf(s1g[1]*INV512 - m1*m1 + 1e-5f);
      const int j0 = bid*16;
#pragma unroll
      for (int rr = 0; rr < 2; ++rr) {
        const int r = w + rr*8, j = j0 + r;
        const float* wr = caWo + ((size_t)i*HS + j)*HS;
        float acc = 0;
#pragma unroll
        for (int k = 0; k < 8; ++k) { int e = lane + 64*k; acc += wr[e]*sh_vec[e]; }
        acc = wred(acc);
        if (lane == 0) {
          float x1j = (t1g[j]-m1)*r1*lnG[(i*3+0)*HS + j] + lnB[(i*3+0)*HS + j];
          float t2v = x1j + acc + caBo[i*HS + j];
          t2g[j] = t2v;
          sh_aux[r] = t2v;
        }
      }
      __syncthreads();
      if (w == 0 && lane < 16) {
        float v = sh_aux[lane], s_ = v, q_ = v*v;
#pragma unroll
        for (int m = 8; m; m >>= 1) { s_ += __shfl_xor(s_, m); q_ += __shfl_xor(q_, m); }
        if (lane == 0) { atomicAdd(&s2g[0], s_); atomicAdd(&s2g[1], q_); }
      }
    }
    gridbar(bcnt, bgen);
    // ---------- H5: ff1 = relu(W1@x2+b1); Y2 += W2[:,chunk]@ff1[chunk] ----------
    {
      const float m2 = s2g[0]*INV512;
      const float r2 = rsqrtf(s2g[1]*INV512 - m2*m2 + 1e-5f);
      sh_vec[tid] = (t2g[tid]-m2)*r2*lnG[(i*3+1)*HS + tid] + lnB[(i*3+1)*HS + tid];
      __syncthreads();
      const int kk = bid*8 + w;
      const float* wr = ffW1 + ((size_t)i*FFD + kk)*HS;
      float acc = 0;
#pragma unroll
      for (int k = 0; k < 8; ++k) { int e = lane + 64*k; acc += wr[e]*sh_vec[e]; }
      acc = wred(acc);
      if (lane == 0) sh_aux[w] = fmaxf(acc + ffB1[i*FFD + kk], 0.f);
      __syncthreads();
      float yl = 0;
#pragma unroll
      for (int r = 0; r < 8; ++r)
        yl += sh_aux[r] * W2T[((size_t)i*FFD + bid*8 + r)*HS + tid];
      atomicAdd(&Y2g[tid], yl);
    }
    gridbar(bcnt, bgen);
  }

  // ---------- final: update for (t=127, i=3) + output assembly ----------
  if (bid == 0) {
    float xn, cn;
    do_update(3, 1, tid, t2g, s2g, Y2g, z02g, cG, lnG, lnB, ffB2, sh_red, w, lane, xn, cn);
    out[127*HS + tid] = xn;
    out[TT*HS + 3*HS + tid] = xn;                 // h_T[3]
    out[TT*HS + LNUM*HS + 3*HS + tid] = cn;       // c_T[3]
#pragma unroll
    for (int ii = 0; ii < 3; ++ii) {
      out[TT*HS + ii*HS + tid]            = hG[(0*LNUM + ii)*HS + tid];
      out[TT*HS + LNUM*HS + ii*HS + tid]  = cG[(0*LNUM + ii)*HS + tid];
    }
  }
}

// ---------------- host launcher ----------------
extern "C" void kernel_launch(void* const* d_in, const int* in_sizes, int n_in,
                              void* d_out, int out_size, void* d_ws, size_t ws_size,
                              hipStream_t stream) {
  const float* x      = (const float*)d_in[0];
  const float* hist   = (const float*)d_in[1];
  const float* Wx     = (const float*)d_in[2];
  const float* bx     = (const float*)d_in[3];
  const float* Wh     = (const float*)d_in[4];
  const float* bh     = (const float*)d_in[5];
  const float* saWin  = (const float*)d_in[6];
  const float* saBin  = (const float*)d_in[7];
  const float* saWo   = (const float*)d_in[8];
  const float* saBo   = (const float*)d_in[9];
  const float* caWin  = (const float*)d_in[10];
  const float* caBin  = (const float*)d_in[11];
  const float* caWo   = (const float*)d_in[12];
  const float* caBo   = (const float*)d_in[13];
  const float* ffW1   = (const float*)d_in[14];
  const float* ffB1   = (const float*)d_in[15];
  const float* ffW2   = (const float*)d_in[16];
  const float* ffB2   = (const float*)d_in[17];
  const float* lnG    = (const float*)d_in[18];
  const float* lnB    = (const float*)d_in[19];
  float* ws  = (float*)d_ws;
  float* out = (float*)d_out;

  // zero the mutable state / accumulators / barrier region
  hipMemsetAsync((char*)d_ws + OFF_STATE*sizeof(float), 0,
                 (WS_TOTAL - OFF_STATE)*sizeof(float), stream);

  // precompute: K, V
  kv_gemm<<<dim3(MMEM/64, HS/64, LNUM), 256, 0, stream>>>(hist, caWin, caBin, ws + OFF_K, HS);
  kv_gemm<<<dim3(MMEM/64, HS/64, LNUM), 256, 0, stream>>>(hist, caWin, caBin, ws + OFF_V, 2*HS);
  // precompute: combined self-attn matrix + bias
  wcomb_gemm<<<dim3(HS/64, HS/64, LNUM), 256, 0, stream>>>(saWo, saWin, ws + OFF_WCOMB);
  csa_kernel<<<(LNUM*HS)/4, 256, 0, stream>>>(saWo, saBin, saBo, ws + OFF_CSA);
  // precompute: WqT (gamma-folded transpose), rowsums, const
  transpose_scale<<<dim3(HS/32, HS/32, LNUM), 256, 0, stream>>>(
      caWin, (size_t)(3*HS)*HS, HS, HS, lnG, (size_t)(3*HS), ws + OFF_WQT, (size_t)HS*HS);
  sqcbq_kernel<<<(LNUM*HS)/4, 256, 0, stream>>>(caWin, caBin, lnG, lnB, ws + OFF_SQ, ws + OFF_CBQ);
  // precompute: W2 transpose
  transpose_scale<<<dim3(FFD/32, HS/32, LNUM), 256, 0, stream>>>(
      ffW2, (size_t)HS*FFD, HS, FFD, nullptr, 0, ws + OFF_W2T, (size_t)FFD*HS);

  // persistent sequential kernel
  seq_kernel<<<NB, NT, 0, stream>>>(x, Wx, bx, Wh, bh, caWo, caBo,
                                    ffW1, ffB1, ffB2, lnG, lnB, ws, out);
}

// Round 2
// 35255.222 us; speedup vs baseline: 2.9940x; 2.9940x over previous
//
#include <hip/hip_runtime.h>

#define HS   512
#define LNUM 4
#define TT   128
#define MMEM 2048
#define FFD  2048
#define NB   256
#define NT   512
#define INV512 (1.0f/512.0f)
#define QSCALE 0.08838834764831845f  // 1/sqrt(128)

// ---------------- workspace layout (float offsets) ----------------
constexpr size_t OFF_K     = 0;                                   // L*M*HS
constexpr size_t OFF_V     = OFF_K     + (size_t)LNUM*MMEM*HS;    // L*M*HS
constexpr size_t OFF_WCOMB = OFF_V     + (size_t)LNUM*MMEM*HS;    // L*HS*HS
constexpr size_t OFF_WQT   = OFF_WCOMB + (size_t)LNUM*HS*HS;      // L*HS*HS (Wq^T * g1 folded)
constexpr size_t OFF_W2T   = OFF_WQT   + (size_t)LNUM*HS*HS;      // L*FF*HS
constexpr size_t OFF_CSA   = OFF_W2T   + (size_t)LNUM*FFD*HS;     // L*HS
constexpr size_t OFF_SQ    = OFF_CSA   + (size_t)LNUM*HS;         // L*HS
constexpr size_t OFF_CBQ   = OFF_SQ    + (size_t)LNUM*HS;         // L*HS
constexpr size_t OFF_STATE = OFF_CBQ   + (size_t)LNUM*HS;
constexpr size_t OFF_H     = OFF_STATE;                           // 2*L*HS
constexpr size_t OFF_C     = OFF_H     + 2*LNUM*HS;               // 2*L*HS
constexpr size_t OFF_XING  = OFF_C     + 2*LNUM*HS;               // HS
constexpr size_t OFF_Z1    = OFF_XING  + HS;                      // HS
constexpr size_t OFF_Z02   = OFF_Z1    + HS;                      // 2*HS
constexpr size_t OFF_T1    = OFF_Z02   + 2*HS;                    // HS
constexpr size_t OFF_T2    = OFF_T1    + HS;                      // HS
constexpr size_t OFF_Y     = OFF_T2    + HS;                      // HS
constexpr size_t OFF_Y2    = OFF_Y     + HS;                      // HS
constexpr size_t OFF_CTX   = OFF_Y2    + HS;                      // HS
constexpr size_t OFF_DEN   = OFF_CTX   + HS;                      // 4
constexpr size_t OFF_S1    = OFF_DEN   + 4;                       // 2
constexpr size_t OFF_S2    = OFF_S1    + 2;                       // 2
// flag-array barrier: one 128B line per block + one release line
constexpr size_t OFF_FLAGS = OFF_S2    + 2;                       // NB*32 u32
constexpr size_t OFF_REL   = OFF_FLAGS + (size_t)NB*32;           // 32
constexpr size_t WS_TOTAL  = OFF_REL   + 32;

__device__ __forceinline__ float wred(float v) {
#pragma unroll
  for (int m = 32; m; m >>= 1) v += __shfl_xor(v, m);
  return v;
}
__device__ __forceinline__ float sigm(float x) { return 1.0f/(1.0f+__expf(-x)); }

// Flag-array grid barrier: parallel arrival on distinct cache lines,
// block 0 detects with one polling thread per flag, single release word.
__device__ __forceinline__ void gridbar(unsigned* flags, unsigned* release, unsigned g) {
  __syncthreads();
  const int tid = threadIdx.x;
  if (blockIdx.x == 0) {
    if (tid >= 1 && tid < NB) {
      unsigned* f = flags + (size_t)tid*32;
      while (__hip_atomic_load(f, __ATOMIC_RELAXED, __HIP_MEMORY_SCOPE_AGENT) != g)
        __builtin_amdgcn_s_sleep(1);
    }
    __syncthreads();
    if (tid == 0) {
      __threadfence();   // flush block-0 data (wb) + invalidate for reads (inv)
      __hip_atomic_store(release, g, __ATOMIC_RELAXED, __HIP_MEMORY_SCOPE_AGENT);
    }
    __syncthreads();
  } else {
    if (tid == 0) {
      __threadfence();   // make this block's stage writes visible at agent scope
      __hip_atomic_store(flags + (size_t)blockIdx.x*32, g, __ATOMIC_RELAXED, __HIP_MEMORY_SCOPE_AGENT);
      while (__hip_atomic_load(release, __ATOMIC_RELAXED, __HIP_MEMORY_SCOPE_AGENT) != g)
        __builtin_amdgcn_s_sleep(1);
      __threadfence();   // invalidate caches before consuming other blocks' data
    }
    __syncthreads();
  }
}

// ---------------- precompute kernels ----------------

// C[l,m,f] = sum_e hist[m,l,e]*caWin[l,koff+f,e] + caBin[l,koff+f]   (K: koff=HS, V: koff=2*HS)
__global__ __launch_bounds__(256) void kv_gemm(
    const float* __restrict__ hist, const float* __restrict__ caWin,
    const float* __restrict__ caBin, float* __restrict__ out, int koff) {
  __shared__ float As[16][64];
  __shared__ float Bs[16][64];
  const int l = blockIdx.z, m0 = blockIdx.x*64, f0 = blockIdx.y*64;
  const int tid = threadIdx.x, tm = tid >> 4, tf = tid & 15;
  float acc[4][4] = {};
  for (int e0 = 0; e0 < HS; e0 += 16) {
#pragma unroll
    for (int it = 0; it < 4; ++it) {
      int idx = tid + it*256, k = idx & 15, mm = idx >> 4;
      As[k][mm] = hist[((size_t)(m0+mm)*LNUM + l)*HS + e0 + k];
      Bs[k][mm] = caWin[((size_t)l*(3*HS) + koff + f0 + mm)*HS + e0 + k];
    }
    __syncthreads();
#pragma unroll
    for (int k = 0; k < 16; ++k) {
      float a[4], b[4];
#pragma unroll
      for (int x = 0; x < 4; ++x) { a[x] = As[k][tm*4+x]; b[x] = Bs[k][tf*4+x]; }
#pragma unroll
      for (int x = 0; x < 4; ++x)
#pragma unroll
        for (int y = 0; y < 4; ++y) acc[x][y] += a[x]*b[y];
    }
    __syncthreads();
  }
#pragma unroll
  for (int x = 0; x < 4; ++x)
#pragma unroll
    for (int y = 0; y < 4; ++y) {
      int m = m0 + tm*4 + x, f = f0 + tf*4 + y;
      out[((size_t)l*MMEM + m)*HS + f] = acc[x][y] + caBin[l*(3*HS) + koff + f];
    }
}

// wcomb[l,f,j] = sum_e saWo[l,f,e] * saWin[l,2HS+e,j]
__global__ __launch_bounds__(256) void wcomb_gemm(
    const float* __restrict__ saWo, const float* __restrict__ saWin, float* __restrict__ wcomb) {
  __shared__ float As[16][64];
  __shared__ float Bs[16][64];
  const int l = blockIdx.z, f0 = blockIdx.x*64, j0 = blockIdx.y*64;
  const int tid = threadIdx.x, tm = tid >> 4, tf = tid & 15;
  float acc[4][4] = {};
  for (int e0 = 0; e0 < HS; e0 += 16) {
#pragma unroll
    for (int it = 0; it < 4; ++it) {
      int idx = tid + it*256;
      { int k = idx & 15, ff = idx >> 4;
        As[k][ff] = saWo[((size_t)l*HS + f0+ff)*HS + e0 + k]; }
      { int jj = idx & 63, k = idx >> 6;
        Bs[k][jj] = saWin[((size_t)l*(3*HS) + 2*HS + e0 + k)*HS + j0 + jj]; }
    }
    __syncthreads();
#pragma unroll
    for (int k = 0; k < 16; ++k) {
      float a[4], b[4];
#pragma unroll
      for (int x = 0; x < 4; ++x) { a[x] = As[k][tm*4+x]; b[x] = Bs[k][tf*4+x]; }
#pragma unroll
      for (int x = 0; x < 4; ++x)
#pragma unroll
        for (int y = 0; y < 4; ++y) acc[x][y] += a[x]*b[y];
    }
    __syncthreads();
  }
#pragma unroll
  for (int x = 0; x < 4; ++x)
#pragma unroll
    for (int y = 0; y < 4; ++y)
      wcomb[(size_t)l*HS*HS + (size_t)(f0+tm*4+x)*HS + (j0+tf*4+y)] = acc[x][y];
}

// out[l,e,f] = in[l*inLS + f*C + e] * (g ? g[l*gLS + e] : 1)
__global__ __launch_bounds__(256) void transpose_scale(
    const float* __restrict__ in, size_t inLS, int R, int C,
    const float* __restrict__ g, size_t gLS, float* __restrict__ out, size_t outLS) {
  __shared__ float tile[32][33];
  const int l = blockIdx.z, e0 = blockIdx.x*32, f0 = blockIdx.y*32;
  const int tx = threadIdx.x & 31, ty = threadIdx.x >> 5;  // ty 0..7
#pragma unroll
  for (int r = 0; r < 32; r += 8)
    tile[ty+r][tx] = in[(size_t)l*inLS + (size_t)(f0+ty+r)*C + e0 + tx];
  __syncthreads();
#pragma unroll
  for (int r = 0; r < 32; r += 8) {
    int e = e0 + ty + r, f = f0 + tx;
    float s = g ? g[(size_t)l*gLS + e] : 1.0f;
    out[(size_t)l*outLS + (size_t)e*R + f] = tile[tx][ty+r] * s;
  }
}

// csa[l,f] = sum_e saWo[l,f,e]*sa_bin[l,2HS+e] + sa_bo[l,f]
__global__ __launch_bounds__(256) void csa_kernel(
    const float* __restrict__ saWo, const float* __restrict__ sabin,
    const float* __restrict__ sabo, float* __restrict__ csa) {
  const int w = threadIdx.x >> 6, lane = threadIdx.x & 63;
  const int row = blockIdx.x*4 + w;
  const int l = row >> 9, f = row & 511;
  float acc = 0;
#pragma unroll
  for (int k = 0; k < 8; ++k) {
    int e = lane + 64*k;
    acc += saWo[((size_t)l*HS + f)*HS + e] * sabin[l*(3*HS) + 2*HS + e];
  }
  acc = wred(acc);
  if (lane == 0) csa[row] = acc + sabo[l*HS + f];
}

// sq[l,f] = sum_e Wq[f,e]*g1[e];  cbq[l,f] = sum_e Wq[f,e]*b1[e] + ca_bin[l,f]
__global__ __launch_bounds__(256) void sqcbq_kernel(
    const float* __restrict__ caWin, const float* __restrict__ caBin,
    const float* __restrict__ lnG, const float* __restrict__ lnB,
    float* __restrict__ sq, float* __restrict__ cbq) {
  const int w = threadIdx.x >> 6, lane = threadIdx.x & 63;
  const int row = blockIdx.x*4 + w;
  const int l = row >> 9, f = row & 511;
  float a1 = 0, a2 = 0;
#pragma unroll
  for (int k = 0; k < 8; ++k) {
    int e = lane + 64*k;
    float wv = caWin[((size_t)l*(3*HS) + f)*HS + e];
    a1 += wv * lnG[l*(3*HS) + e];
    a2 += wv * lnB[l*(3*HS) + e];
  }
  a1 = wred(a1); a2 = wred(a2);
  if (lane == 0) { sq[row] = a1; cbq[row] = a2 + caBin[l*(3*HS) + f]; }
}

// ---------------- main persistent sequential kernel ----------------

__device__ __forceinline__ void do_update(
    int ip, int parp, int j,
    const float* __restrict__ t2g, const float* __restrict__ s2g,
    const float* __restrict__ Y2g, const float* __restrict__ z02g,
    const float* __restrict__ cG,
    const float* __restrict__ lnG, const float* __restrict__ lnB,
    const float* __restrict__ ffB2,
    float* sh_red, int w, int lane, float& xn, float& cn) {
  float m2 = s2g[0]*INV512;
  float r2 = rsqrtf(s2g[1]*INV512 - m2*m2 + 1e-5f);
  float x2 = (t2g[j]-m2)*r2*lnG[(ip*3+1)*HS+j] + lnB[(ip*3+1)*HS+j];
  float t3 = x2 + Y2g[j] + ffB2[ip*HS + j];
  float s_ = t3, q_ = t3*t3;
#pragma unroll
  for (int m = 32; m; m >>= 1) { s_ += __shfl_xor(s_, m); q_ += __shfl_xor(q_, m); }
  if (lane == 0) { sh_red[w] = s_; sh_red[8+w] = q_; }
  __syncthreads();
  if (threadIdx.x == 0) {
    float a = 0, b = 0;
#pragma unroll
    for (int k = 0; k < 8; ++k) { a += sh_red[k]; b += sh_red[8+k]; }
    sh_red[0] = a; sh_red[1] = b;
  }
  __syncthreads();
  float m3 = sh_red[0]*INV512;
  float r3 = rsqrtf(sh_red[1]*INV512 - m3*m3 + 1e-5f);
  float d  = (t3-m3)*r3*lnG[(ip*3+2)*HS+j] + lnB[(ip*3+2)*HS+j];
  float cp = cG[(parp*LNUM + ip)*HS + j];
  float ft = sigm(cp - d);
  float it = sigm(z02g[j]);
  float gt = tanhf(z02g[HS + j]);
  cn = ft*cp + it*gt;
  xn = tanhf(cn);
}

__global__ __launch_bounds__(NT, 2) void seq_kernel(
    const float* __restrict__ x,
    const float* __restrict__ Wx,  const float* __restrict__ bx,
    const float* __restrict__ Wh,  const float* __restrict__ bh,
    const float* __restrict__ caWo, const float* __restrict__ caBo,
    const float* __restrict__ ffW1, const float* __restrict__ ffB1,
    const float* __restrict__ ffB2,
    const float* __restrict__ lnG,  const float* __restrict__ lnB,
    float* __restrict__ ws, float* __restrict__ out) {
  float* Kb    = ws + OFF_K;
  float* Vb    = ws + OFF_V;
  float* Wcomb = ws + OFF_WCOMB;
  float* WqT   = ws + OFF_WQT;
  float* W2T   = ws + OFF_W2T;
  float* csag  = ws + OFF_CSA;
  float* sqg   = ws + OFF_SQ;
  float* cbqg  = ws + OFF_CBQ;
  float* hG    = ws + OFF_H;
  float* cG    = ws + OFF_C;
  float* xing  = ws + OFF_XING;
  float* z1g   = ws + OFF_Z1;
  float* z02g  = ws + OFF_Z02;
  float* t1g   = ws + OFF_T1;
  float* t2g   = ws + OFF_T2;
  float* Yg    = ws + OFF_Y;
  float* Y2g   = ws + OFF_Y2;
  float* ctxg  = ws + OFF_CTX;
  float* deng  = ws + OFF_DEN;
  float* s1g   = ws + OFF_S1;
  float* s2g   = ws + OFF_S2;
  unsigned* bflags = (unsigned*)(ws + OFF_FLAGS);
  unsigned* brel   = (unsigned*)(ws + OFF_REL);

  __shared__ float sh_xin[HS], sh_h[HS], sh_vec[HS], sh_aux[HS];
  __shared__ float sh_q[128], sh_p[32], sh_red[16];

  const int bid = blockIdx.x, tid = threadIdx.x;
  const int w = tid >> 6, lane = tid & 63;
  unsigned gen = 1;

  for (int s = 0; s < TT*LNUM; ++s) {
    const int t = s >> 2, i = s & 3;
    const int par = t & 1;
    // ---------- H1: update(prev) fused + z gate-1 matvec + accumulator zeroing ----------
    {
      const int ip = (s-1) & 3, tp = (s-1) >> 2, parp = tp & 1;
      const bool upd = (s > 0) && (bid == 0 || (i > 0 && bid < 64));
      float xn = 0.f, cn = 0.f;
      if (upd) {
        do_update(ip, parp, tid, t2g, s2g, Y2g, z02g, cG, lnG, lnB, ffB2, sh_red, w, lane, xn, cn);
        if (bid == 0) {
          hG[((parp^1)*LNUM + ip)*HS + tid] = xn;
          cG[((parp^1)*LNUM + ip)*HS + tid] = cn;
          if (ip == 3) out[tp*HS + tid] = xn;
        }
      }
      if (bid < 64) {
        float xv = (i == 0) ? x[t*HS + tid] : xn;
        sh_xin[tid] = xv;
        sh_h[tid]   = hG[(par*LNUM + i)*HS + tid];
        if (bid == 0) xing[tid] = xv;
      } else if (bid == 64) { Yg[tid] = 0.f; }
      else if (bid == 65)   { ctxg[tid] = 0.f; }
      else if (bid == 66)   { if (tid < 4) deng[tid] = 0.f; else if (tid == 4) s1g[0] = 0.f; else if (tid == 5) s1g[1] = 0.f; }
      __syncthreads();
      if (bid < 64) {
        const int f = bid*8 + w;
        const float* wxr = Wx + (((size_t)i*3 + 1)*HS + f)*HS;
        const float* whr = Wh + (((size_t)i*3 + 1)*HS + f)*HS;
        float acc = 0;
#pragma unroll
        for (int k = 0; k < 8; ++k) {
          int e = lane + 64*k;
          acc += wxr[e]*sh_xin[e] + whr[e]*sh_h[e];
        }
        acc = wred(acc);
        if (lane == 0) z1g[f] = acc + bx[(i*3+1)*HS + f] + bh[(i*3+1)*HS + f];
      }
    }
    gridbar(bflags, brel, gen); ++gen;
    // ---------- H2: t1 = f0 + Wcomb@f0 + csa; deferred q accumulation; stats1 ----------
    if (bid < 32) {
      sh_vec[tid] = sigm(z1g[tid]);  // f0
      __syncthreads();
      const int j0 = bid*16;
#pragma unroll
      for (int rr = 0; rr < 2; ++rr) {
        const int r = w + rr*8, j = j0 + r;
        const float* wr = Wcomb + ((size_t)i*HS + j)*HS;
        float acc = 0;
#pragma unroll
        for (int k = 0; k < 8; ++k) { int e = lane + 64*k; acc += wr[e]*sh_vec[e]; }
        acc = wred(acc);
        if (lane == 0) {
          float t1v = sh_vec[j] + acc + csag[i*HS + j];
          t1g[j] = t1v;
          sh_aux[r] = t1v;
        }
      }
      __syncthreads();
      {
        float yl = 0;
#pragma unroll
        for (int r = 0; r < 16; ++r)
          yl += sh_aux[r] * WqT[((size_t)i*HS + j0 + r)*HS + tid];
        atomicAdd(&Yg[tid], yl);
      }
      if (w == 0 && lane < 16) {
        float v = sh_aux[lane], s_ = v, q_ = v*v;
#pragma unroll
        for (int m = 8; m; m >>= 1) { s_ += __shfl_xor(s_, m); q_ += __shfl_xor(q_, m); }
        if (lane == 0) { atomicAdd(&s1g[0], s_); atomicAdd(&s1g[1], q_); }
      }
    } else if (bid == 32) {
      Y2g[tid] = 0.f;
      if (tid == 0) s2g[0] = 0.f;
      if (tid == 1) s2g[1] = 0.f;
    }
    gridbar(bflags, brel, gen); ++gen;
    // ---------- H3: attention (scores+exp+ctx+den) + z gates 0,2 ----------
    {
      const int h = bid >> 6, mb = (bid & 63)*32;
      sh_xin[tid] = xing[tid];
      sh_h[tid]   = hG[(par*LNUM + i)*HS + tid];
      if (tid < 128) {
        float m1 = s1g[0]*INV512;
        float r1 = rsqrtf(s1g[1]*INV512 - m1*m1 + 1e-5f);
        int f = h*128 + tid;
        sh_q[tid] = r1*(Yg[f] - m1*sqg[i*HS + f]) + cbqg[i*HS + f];
      }
      __syncthreads();
#pragma unroll
      for (int c = 0; c < 4; ++c) {
        const int m_ = mb + w*4 + c;
        const float* kr = Kb + ((size_t)i*MMEM + m_)*HS + h*128;
        float acc = sh_q[lane]*kr[lane] + sh_q[lane+64]*kr[lane+64];
        acc = wred(acc);
        if (lane == 0) sh_p[w*4 + c] = __expf(acc * QSCALE);
      }
      __syncthreads();
      if (w < 2) {
        const int d = tid;  // 0..127
        float acc = 0;
#pragma unroll 8
        for (int ml = 0; ml < 32; ++ml)
          acc += sh_p[ml] * Vb[((size_t)i*MMEM + mb + ml)*HS + h*128 + d];
        atomicAdd(&ctxg[h*128 + d], acc);
      } else if (w == 2) {
        if (lane < 32) {
          float s_ = sh_p[lane];
#pragma unroll
          for (int m = 16; m; m >>= 1) s_ += __shfl_xor(s_, m);
          if (lane == 0) atomicAdd(&deng[h], s_);
        }
      } else if (w >= 4) {
        const int rowid = bid*4 + (w - 4);
        const int g = (rowid < 512) ? 0 : 2;
        const int f = rowid & 511;
        const float* wxr = Wx + (((size_t)i*3 + g)*HS + f)*HS;
        const float* whr = Wh + (((size_t)i*3 + g)*HS + f)*HS;
        float acc = 0;
#pragma unroll
        for (int k = 0; k < 8; ++k) {
          int e = lane + 64*k;
          acc += wxr[e]*sh_xin[e] + whr[e]*sh_h[e];
        }
        acc = wred(acc);
        if (lane == 0) z02g[(g ? HS : 0) + f] = acc + bx[(i*3+g)*HS + f] + bh[(i*3+g)*HS + f];
      }
    }
    gridbar(bflags, brel, gen); ++gen;
    // ---------- H4: t2 = x1 + caWo@(ctx/den) + bo; stats2 ----------
    if (bid < 32) {
      sh_vec[tid] = ctxg[tid] / deng[tid >> 7];
      __syncthreads();
      const float m1 = s1g[0]*INV512;
      const float r1 = rsqrtf(s1g[1]*INV512 - m1*m1 + 1e-5f);
      const int j0 = bid*16;
#pragma unroll
      for (int rr = 0; rr < 2; ++rr) {
        const int r = w + rr*8, j = j0 + r;
        const float* wr = caWo + ((size_t)i*HS + j)*HS;
        float acc = 0;
#pragma unroll
        for (int k = 0; k < 8; ++k) { int e = lane + 64*k; acc += wr[e]*sh_vec[e]; }
        acc = wred(acc);
        if (lane == 0) {
          float x1j = (t1g[j]-m1)*r1*lnG[(i*3+0)*HS + j] + lnB[(i*3+0)*HS + j];
          float t2v = x1j + acc + caBo[i*HS + j];
          t2g[j] = t2v;
          sh_aux[r] = t2v;
        }
      }
      __syncthreads();
      if (w == 0 && lane < 16) {
        float v = sh_aux[lane], s_ = v, q_ = v*v;
#pragma unroll
        for (int m = 8; m; m >>= 1) { s_ += __shfl_xor(s_, m); q_ += __shfl_xor(q_, m); }
        if (lane == 0) { atomicAdd(&s2g[0], s_); atomicAdd(&s2g[1], q_); }
      }
    }
    gridbar(bflags, brel, gen); ++gen;
    // ---------- H5: ff1 = relu(W1@x2+b1); Y2 += W2[:,chunk]@ff1[chunk] ----------
    {
      const float m2 = s2g[0]*INV512;
      const float r2 = rsqrtf(s2g[1]*INV512 - m2*m2 + 1e-5f);
      sh_vec[tid] = (t2g[tid]-m2)*r2*lnG[(i*3+1)*HS + tid] + lnB[(i*3+1)*HS + tid];
      __syncthreads();
      const int kk = bid*8 + w;
      const float* wr = ffW1 + ((size_t)i*FFD + kk)*HS;
      float acc = 0;
#pragma unroll
      for (int k = 0; k < 8; ++k) { int e = lane + 64*k; acc += wr[e]*sh_vec[e]; }
      acc = wred(acc);
      if (lane == 0) sh_aux[w] = fmaxf(acc + ffB1[i*FFD + kk], 0.f);
      __syncthreads();
      float yl = 0;
#pragma unroll
      for (int r = 0; r < 8; ++r)
        yl += sh_aux[r] * W2T[((size_t)i*FFD + bid*8 + r)*HS + tid];
      atomicAdd(&Y2g[tid], yl);
    }
    gridbar(bflags, brel, gen); ++gen;
  }

  // ---------- final: update for (t=127, i=3) + output assembly ----------
  if (bid == 0) {
    float xn, cn;
    do_update(3, 1, tid, t2g, s2g, Y2g, z02g, cG, lnG, lnB, ffB2, sh_red, w, lane, xn, cn);
    out[127*HS + tid] = xn;
    out[TT*HS + 3*HS + tid] = xn;                 // h_T[3]
    out[TT*HS + LNUM*HS + 3*HS + tid] = cn;       // c_T[3]
#pragma unroll
    for (int ii = 0; ii < 3; ++ii) {
      out[TT*HS + ii*HS + tid]            = hG[(0*LNUM + ii)*HS + tid];
      out[TT*HS + LNUM*HS + ii*HS + tid]  = cG[(0*LNUM + ii)*HS + tid];
    }
  }
}

// ---------------- host launcher ----------------
extern "C" void kernel_launch(void* const* d_in, const int* in_sizes, int n_in,
                              void* d_out, int out_size, void* d_ws, size_t ws_size,
                              hipStream_t stream) {
  const float* x      = (const float*)d_in[0];
  const float* hist   = (const float*)d_in[1];
  const float* Wx     = (const float*)d_in[2];
  const float* bx     = (const float*)d_in[3];
  const float* Wh     = (const float*)d_in[4];
  const float* bh     = (const float*)d_in[5];
  const float* saWin  = (const float*)d_in[6];
  const float* saBin  = (const float*)d_in[7];
  const float* saWo   = (const float*)d_in[8];
  const float* saBo   = (const float*)d_in[9];
  const float* caWin  = (const float*)d_in[10];
  const float* caBin  = (const float*)d_in[11];
  const float* caWo   = (const float*)d_in[12];
  const float* caBo   = (const float*)d_in[13];
  const float* ffW1   = (const float*)d_in[14];
  const float* ffB1   = (const float*)d_in[15];
  const float* ffW2   = (const float*)d_in[16];
  const float* ffB2   = (const float*)d_in[17];
  const float* lnG    = (const float*)d_in[18];
  const float* lnB    = (const float*)d_in[19];
  float* ws  = (float*)d_ws;
  float* out = (float*)d_out;

  // zero the mutable state / accumulators / barrier region
  hipMemsetAsync((char*)d_ws + OFF_STATE*sizeof(float), 0,
                 (WS_TOTAL - OFF_STATE)*sizeof(float), stream);

  // precompute: K, V
  kv_gemm<<<dim3(MMEM/64, HS/64, LNUM), 256, 0, stream>>>(hist, caWin, caBin, ws + OFF_K, HS);
  kv_gemm<<<dim3(MMEM/64, HS/64, LNUM), 256, 0, stream>>>(hist, caWin, caBin, ws + OFF_V, 2*HS);
  // precompute: combined self-attn matrix + bias
  wcomb_gemm<<<dim3(HS/64, HS/64, LNUM), 256, 0, stream>>>(saWo, saWin, ws + OFF_WCOMB);
  csa_kernel<<<(LNUM*HS)/4, 256, 0, stream>>>(saWo, saBin, saBo, ws + OFF_CSA);
  // precompute: WqT (gamma-folded transpose), rowsums, const
  transpose_scale<<<dim3(HS/32, HS/32, LNUM), 256, 0, stream>>>(
      caWin, (size_t)(3*HS)*HS, HS, HS, lnG, (size_t)(3*HS), ws + OFF_WQT, (size_t)HS*HS);
  sqcbq_kernel<<<(LNUM*HS)/4, 256, 0, stream>>>(caWin, caBin, lnG, lnB, ws + OFF_SQ, ws + OFF_CBQ);
  // precompute: W2 transpose
  transpose_scale<<<dim3(FFD/32, HS/32, LNUM), 256, 0, stream>>>(
      ffW2, (size_t)HS*FFD, HS, FFD, nullptr, 0, ws + OFF_W2T, (size_t)FFD*HS);

  // persistent sequential kernel
  seq_kernel<<<NB, NT, 0, stream>>>(x, Wx, bx, Wh, bh, caWo, caBo,
                                    ffW1, ffB1, ffB2, lnG, lnB, ws, out);
}

// Round 3
// 15022.798 us; speedup vs baseline: 7.0264x; 2.3468x over previous
//
#include <hip/hip_runtime.h>

#define HS   512
#define LNUM 4
#define TT   128
#define MMEM 2048
#define FFD  2048
#define NB   256
#define NT   512
#define INV512 (1.0f/512.0f)
#define QSCALE 0.08838834764831845f  // 1/sqrt(128)

// ---------------- workspace layout (float offsets) ----------------
constexpr size_t OFF_K     = 0;                                   // L*M*HS
constexpr size_t OFF_V     = OFF_K     + (size_t)LNUM*MMEM*HS;    // L*M*HS
constexpr size_t OFF_WCOMB = OFF_V     + (size_t)LNUM*MMEM*HS;    // L*HS*HS
constexpr size_t OFF_WQT   = OFF_WCOMB + (size_t)LNUM*HS*HS;      // L*HS*HS
constexpr size_t OFF_W2T   = OFF_WQT   + (size_t)LNUM*HS*HS;      // L*FF*HS
constexpr size_t OFF_CSA   = OFF_W2T   + (size_t)LNUM*FFD*HS;     // L*HS
constexpr size_t OFF_SQ    = OFF_CSA   + (size_t)LNUM*HS;         // L*HS
constexpr size_t OFF_CBQ   = OFF_SQ    + (size_t)LNUM*HS;         // L*HS
constexpr size_t OFF_STATE = OFF_CBQ   + (size_t)LNUM*HS;
constexpr size_t OFF_H     = OFF_STATE;                           // 2*L*HS
constexpr size_t OFF_C     = OFF_H     + 2*LNUM*HS;               // 2*L*HS
constexpr size_t OFF_XING  = OFF_C     + 2*LNUM*HS;               // HS
constexpr size_t OFF_Z1    = OFF_XING  + HS;                      // HS
constexpr size_t OFF_Z02   = OFF_Z1    + HS;                      // 2*HS
constexpr size_t OFF_T2    = OFF_Z02   + 2*HS;                    // HS
constexpr size_t OFF_Y     = OFF_T2    + HS;                      // HS
constexpr size_t OFF_Y2    = OFF_Y     + HS;                      // 4*HS (4 planes)
constexpr size_t OFF_CTX   = OFF_Y2    + 4*HS;                    // 2*HS (2 planes)
constexpr size_t OFF_DEN   = OFF_CTX   + 2*HS;                    // 4
constexpr size_t OFF_S1    = OFF_DEN   + 4;                       // 2
constexpr size_t OFF_S2    = OFF_S1    + 2;                       // 2
constexpr size_t OFF_FLAGS = OFF_S2    + 2;                       // NB*32 u32
constexpr size_t OFF_REL   = OFF_FLAGS + (size_t)NB*32;           // 32
constexpr size_t WS_TOTAL  = OFF_REL   + 32;

__device__ __forceinline__ float wred(float v) {
#pragma unroll
  for (int m = 32; m; m >>= 1) v += __shfl_xor(v, m);
  return v;
}
__device__ __forceinline__ float sigm(float x) { return 1.0f/(1.0f+__expf(-x)); }

// agent-scope coherent accessors (bypass L1/L2 to coherence point)
__device__ __forceinline__ float ald(const float* p) {
  return __hip_atomic_load(p, __ATOMIC_RELAXED, __HIP_MEMORY_SCOPE_AGENT);
}
__device__ __forceinline__ void ast(float* p, float v) {
  __hip_atomic_store(p, v, __ATOMIC_RELAXED, __HIP_MEMORY_SCOPE_AGENT);
}

// Split barrier: drain stores -> arrive -> prefetch (overlaps wait) -> wait.
// No cache-flushing fences: all cross-block data moves via agent-scope atomics.
template <class F>
__device__ __forceinline__ void barrier_pf(unsigned* flags, unsigned* release,
                                           unsigned g, F&& pf) {
  asm volatile("s_waitcnt vmcnt(0)" ::: "memory");
  __syncthreads();
  const int tid = threadIdx.x;
  if (blockIdx.x == 0) {
    pf();
    if (tid >= 1 && tid < NB) {
      unsigned* f = flags + (size_t)tid*32;
      while (__hip_atomic_load(f, __ATOMIC_RELAXED, __HIP_MEMORY_SCOPE_AGENT) != g)
        __builtin_amdgcn_s_sleep(1);
    }
    __syncthreads();
    if (tid == 0)
      __hip_atomic_store(release, g, __ATOMIC_RELAXED, __HIP_MEMORY_SCOPE_AGENT);
  } else {
    if (tid == 0)
      __hip_atomic_store(flags + (size_t)blockIdx.x*32, g, __ATOMIC_RELAXED, __HIP_MEMORY_SCOPE_AGENT);
    pf();
    if (tid == 0) {
      while (__hip_atomic_load(release, __ATOMIC_RELAXED, __HIP_MEMORY_SCOPE_AGENT) != g)
        __builtin_amdgcn_s_sleep(1);
    }
    __syncthreads();
  }
}

// ---------------- precompute kernels (unchanged) ----------------

__global__ __launch_bounds__(256) void kv_gemm(
    const float* __restrict__ hist, const float* __restrict__ caWin,
    const float* __restrict__ caBin, float* __restrict__ out, int koff) {
  __shared__ float As[16][64];
  __shared__ float Bs[16][64];
  const int l = blockIdx.z, m0 = blockIdx.x*64, f0 = blockIdx.y*64;
  const int tid = threadIdx.x, tm = tid >> 4, tf = tid & 15;
  float acc[4][4] = {};
  for (int e0 = 0; e0 < HS; e0 += 16) {
#pragma unroll
    for (int it = 0; it < 4; ++it) {
      int idx = tid + it*256, k = idx & 15, mm = idx >> 4;
      As[k][mm] = hist[((size_t)(m0+mm)*LNUM + l)*HS + e0 + k];
      Bs[k][mm] = caWin[((size_t)l*(3*HS) + koff + f0 + mm)*HS + e0 + k];
    }
    __syncthreads();
#pragma unroll
    for (int k = 0; k < 16; ++k) {
      float a[4], b[4];
#pragma unroll
      for (int x = 0; x < 4; ++x) { a[x] = As[k][tm*4+x]; b[x] = Bs[k][tf*4+x]; }
#pragma unroll
      for (int x = 0; x < 4; ++x)
#pragma unroll
        for (int y = 0; y < 4; ++y) acc[x][y] += a[x]*b[y];
    }
    __syncthreads();
  }
#pragma unroll
  for (int x = 0; x < 4; ++x)
#pragma unroll
    for (int y = 0; y < 4; ++y) {
      int m = m0 + tm*4 + x, f = f0 + tf*4 + y;
      out[((size_t)l*MMEM + m)*HS + f] = acc[x][y] + caBin[l*(3*HS) + koff + f];
    }
}

__global__ __launch_bounds__(256) void wcomb_gemm(
    const float* __restrict__ saWo, const float* __restrict__ saWin, float* __restrict__ wcomb) {
  __shared__ float As[16][64];
  __shared__ float Bs[16][64];
  const int l = blockIdx.z, f0 = blockIdx.x*64, j0 = blockIdx.y*64;
  const int tid = threadIdx.x, tm = tid >> 4, tf = tid & 15;
  float acc[4][4] = {};
  for (int e0 = 0; e0 < HS; e0 += 16) {
#pragma unroll
    for (int it = 0; it < 4; ++it) {
      int idx = tid + it*256;
      { int k = idx & 15, ff = idx >> 4;
        As[k][ff] = saWo[((size_t)l*HS + f0+ff)*HS + e0 + k]; }
      { int jj = idx & 63, k = idx >> 6;
        Bs[k][jj] = saWin[((size_t)l*(3*HS) + 2*HS + e0 + k)*HS + j0 + jj]; }
    }
    __syncthreads();
#pragma unroll
    for (int k = 0; k < 16; ++k) {
      float a[4], b[4];
#pragma unroll
      for (int x = 0; x < 4; ++x) { a[x] = As[k][tm*4+x]; b[x] = Bs[k][tf*4+x]; }
#pragma unroll
      for (int x = 0; x < 4; ++x)
#pragma unroll
        for (int y = 0; y < 4; ++y) acc[x][y] += a[x]*b[y];
    }
    __syncthreads();
  }
#pragma unroll
  for (int x = 0; x < 4; ++x)
#pragma unroll
    for (int y = 0; y < 4; ++y)
      wcomb[(size_t)l*HS*HS + (size_t)(f0+tm*4+x)*HS + (j0+tf*4+y)] = acc[x][y];
}

__global__ __launch_bounds__(256) void transpose_scale(
    const float* __restrict__ in, size_t inLS, int R, int C,
    const float* __restrict__ g, size_t gLS, float* __restrict__ out, size_t outLS) {
  __shared__ float tile[32][33];
  const int l = blockIdx.z, e0 = blockIdx.x*32, f0 = blockIdx.y*32;
  const int tx = threadIdx.x & 31, ty = threadIdx.x >> 5;
#pragma unroll
  for (int r = 0; r < 32; r += 8)
    tile[ty+r][tx] = in[(size_t)l*inLS + (size_t)(f0+ty+r)*C + e0 + tx];
  __syncthreads();
#pragma unroll
  for (int r = 0; r < 32; r += 8) {
    int e = e0 + ty + r, f = f0 + tx;
    float s = g ? g[(size_t)l*gLS + e] : 1.0f;
    out[(size_t)l*outLS + (size_t)e*R + f] = tile[tx][ty+r] * s;
  }
}

__global__ __launch_bounds__(256) void csa_kernel(
    const float* __restrict__ saWo, const float* __restrict__ sabin,
    const float* __restrict__ sabo, float* __restrict__ csa) {
  const int w = threadIdx.x >> 6, lane = threadIdx.x & 63;
  const int row = blockIdx.x*4 + w;
  const int l = row >> 9, f = row & 511;
  float acc = 0;
#pragma unroll
  for (int k = 0; k < 8; ++k) {
    int e = lane + 64*k;
    acc += saWo[((size_t)l*HS + f)*HS + e] * sabin[l*(3*HS) + 2*HS + e];
  }
  acc = wred(acc);
  if (lane == 0) csa[row] = acc + sabo[l*HS + f];
}

__global__ __launch_bounds__(256) void sqcbq_kernel(
    const float* __restrict__ caWin, const float* __restrict__ caBin,
    const float* __restrict__ lnG, const float* __restrict__ lnB,
    float* __restrict__ sq, float* __restrict__ cbq) {
  const int w = threadIdx.x >> 6, lane = threadIdx.x & 63;
  const int row = blockIdx.x*4 + w;
  const int l = row >> 9, f = row & 511;
  float a1 = 0, a2 = 0;
#pragma unroll
  for (int k = 0; k < 8; ++k) {
    int e = lane + 64*k;
    float wv = caWin[((size_t)l*(3*HS) + f)*HS + e];
    a1 += wv * lnG[l*(3*HS) + e];
    a2 += wv * lnB[l*(3*HS) + e];
  }
  a1 = wred(a1); a2 = wred(a2);
  if (lane == 0) { sq[row] = a1; cbq[row] = a2 + caBin[l*(3*HS) + f]; }
}

// ---------------- main persistent sequential kernel ----------------

__device__ __forceinline__ void do_update(
    int ip, int parp, int j,
    const float* t2g, const float* s2g, const float* Y2g,
    const float* z02g, const float* cG,
    const float* __restrict__ lnG, const float* __restrict__ lnB,
    const float* __restrict__ ffB2,
    float* sh_red, int w, int lane, float& xn, float& cn) {
  float s20 = ald(s2g), s21 = ald(s2g + 1);
  float m2 = s20*INV512;
  float r2 = rsqrtf(s21*INV512 - m2*m2 + 1e-5f);
  float t2v = ald(t2g + j);
  float x2 = (t2v-m2)*r2*lnG[(ip*3+1)*HS+j] + lnB[(ip*3+1)*HS+j];
  float y2 = ald(Y2g + j) + ald(Y2g + HS + j) + ald(Y2g + 2*HS + j) + ald(Y2g + 3*HS + j);
  float t3 = x2 + y2 + ffB2[ip*HS + j];
  float s_ = t3, q_ = t3*t3;
#pragma unroll
  for (int m = 32; m; m >>= 1) { s_ += __shfl_xor(s_, m); q_ += __shfl_xor(q_, m); }
  if (lane == 0) { sh_red[w] = s_; sh_red[8+w] = q_; }
  __syncthreads();
  if (threadIdx.x == 0) {
    float a = 0, b = 0;
#pragma unroll
    for (int k = 0; k < 8; ++k) { a += sh_red[k]; b += sh_red[8+k]; }
    sh_red[0] = a; sh_red[1] = b;
  }
  __syncthreads();
  float m3 = sh_red[0]*INV512;
  float r3 = rsqrtf(sh_red[1]*INV512 - m3*m3 + 1e-5f);
  float d  = (t3-m3)*r3*lnG[(ip*3+2)*HS+j] + lnB[(ip*3+2)*HS+j];
  float cp = ald(cG + (parp*LNUM + ip)*HS + j);
  float z0 = ald(z02g + j);
  float z2 = ald(z02g + HS + j);
  float ft = sigm(cp - d);
  float it = sigm(z0);
  float gt = tanhf(z2);
  cn = ft*cp + it*gt;
  xn = tanhf(cn);
}

__global__ __launch_bounds__(NT, 2) void seq_kernel(
    const float* __restrict__ x,
    const float* __restrict__ Wx,  const float* __restrict__ bx,
    const float* __restrict__ Wh,  const float* __restrict__ bh,
    const float* __restrict__ caWo, const float* __restrict__ caBo,
    const float* __restrict__ ffW1, const float* __restrict__ ffB1,
    const float* __restrict__ ffB2,
    const float* __restrict__ lnG,  const float* __restrict__ lnB,
    float* __restrict__ ws, float* __restrict__ out) {
  const float* Kb    = ws + OFF_K;
  const float* Vb    = ws + OFF_V;
  const float* Wcomb = ws + OFF_WCOMB;
  const float* WqT   = ws + OFF_WQT;
  const float* W2T   = ws + OFF_W2T;
  const float* csag  = ws + OFF_CSA;
  const float* sqg   = ws + OFF_SQ;
  const float* cbqg  = ws + OFF_CBQ;
  float* hG    = ws + OFF_H;
  float* cG    = ws + OFF_C;
  float* xing  = ws + OFF_XING;
  float* z1g   = ws + OFF_Z1;
  float* z02g  = ws + OFF_Z02;
  float* t2g   = ws + OFF_T2;
  float* Yg    = ws + OFF_Y;
  float* Y2g   = ws + OFF_Y2;
  float* ctxg  = ws + OFF_CTX;
  float* deng  = ws + OFF_DEN;
  float* s1g   = ws + OFF_S1;
  float* s2g   = ws + OFF_S2;
  unsigned* bflags = (unsigned*)(ws + OFF_FLAGS);
  unsigned* brel   = (unsigned*)(ws + OFF_REL);

  __shared__ float sh_xin[HS], sh_h[HS], sh_vec[HS], sh_aux[HS];
  __shared__ float sh_q[128], sh_p[32], sh_red[16], sh_t1[16];

  const int bid = blockIdx.x, tid = threadIdx.x;
  const int w = tid >> 6, lane = tid & 63;
  unsigned gen = 1;

  // prefetch register files
  float pH1wx[8], pH1wh[8];
  float pH2wc[2][8], pH2wq[16];
  float pH2zx[8], pH2zh[8];
  float pH3k[4][2], pH3v[16];
  float pH4ca[2][8];
  float pH5f1[8], pH5w2[8];

  auto pfH1 = [&](int l) {
    if (bid < 64) {
      const float* wxr = Wx + (((size_t)l*3 + 1)*HS + bid*8 + w)*HS;
      const float* whr = Wh + (((size_t)l*3 + 1)*HS + bid*8 + w)*HS;
#pragma unroll
      for (int k = 0; k < 8; ++k) { pH1wx[k] = wxr[lane+64*k]; pH1wh[k] = whr[lane+64*k]; }
    }
  };
  auto pfH2 = [&](int l) {
    if (bid < 32) {
#pragma unroll
      for (int rr = 0; rr < 2; ++rr) {
        const float* wr = Wcomb + ((size_t)l*HS + bid*16 + w + rr*8)*HS;
#pragma unroll
        for (int k = 0; k < 8; ++k) pH2wc[rr][k] = wr[lane+64*k];
      }
#pragma unroll
      for (int r = 0; r < 16; ++r)
        pH2wq[r] = WqT[((size_t)l*HS + bid*16 + r)*HS + tid];
    } else if (bid >= 128) {
      const int rowid = (bid-128)*8 + w;
      const int g = (rowid < 512) ? 0 : 2;
      const int f = rowid & 511;
      const float* wxr = Wx + (((size_t)l*3 + g)*HS + f)*HS;
      const float* whr = Wh + (((size_t)l*3 + g)*HS + f)*HS;
#pragma unroll
      for (int k = 0; k < 8; ++k) { pH2zx[k] = wxr[lane+64*k]; pH2zh[k] = whr[lane+64*k]; }
    }
  };
  auto pfH3 = [&](int l) {
    const int h = bid >> 6, mb = (bid & 63)*32;
#pragma unroll
    for (int c = 0; c < 4; ++c) {
      const float* kr = Kb + ((size_t)l*MMEM + mb + w*4 + c)*HS + h*128;
      pH3k[c][0] = kr[lane]; pH3k[c][1] = kr[lane+64];
    }
    if (w < 2) {
#pragma unroll
      for (int ml = 0; ml < 16; ++ml)
        pH3v[ml] = Vb[((size_t)l*MMEM + mb + ml)*HS + h*128 + tid];
    } else if (w == 4 || w == 5) {
#pragma unroll
      for (int ml = 0; ml < 16; ++ml)
        pH3v[ml] = Vb[((size_t)l*MMEM + mb + 16 + ml)*HS + h*128 + (tid - 256)];
    }
  };
  auto pfH4 = [&](int l) {
    if (bid < 32) {
#pragma unroll
      for (int rr = 0; rr < 2; ++rr) {
        const float* wr = caWo + ((size_t)l*HS + bid*16 + w + rr*8)*HS;
#pragma unroll
        for (int k = 0; k < 8; ++k) pH4ca[rr][k] = wr[lane+64*k];
      }
    }
  };
  auto pfH5 = [&](int l) {
    const float* wr = ffW1 + ((size_t)l*FFD + bid*8 + w)*HS;
#pragma unroll
    for (int k = 0; k < 8; ++k) pH5f1[k] = wr[lane+64*k];
#pragma unroll
    for (int r = 0; r < 8; ++r)
      pH5w2[r] = W2T[((size_t)l*FFD + bid*8 + r)*HS + tid];
  };

  pfH1(0);

  for (int s = 0; s < TT*LNUM; ++s) {
    const int t = s >> 2, i = s & 3;
    const int par = t & 1;
    // ---------- H1: fused update(prev) + z gate-1 matvec + accumulator zeroing ----------
    {
      const int ip = (s-1) & 3, tp = (s-1) >> 2, parp = tp & 1;
      const bool upd = (s > 0) && (bid == 0 || (i > 0 && bid < 64));
      float xn = 0.f, cn = 0.f;
      if (upd) {
        do_update(ip, parp, tid, t2g, s2g, Y2g, z02g, cG, lnG, lnB, ffB2, sh_red, w, lane, xn, cn);
        if (bid == 0) {
          ast(hG + ((parp^1)*LNUM + ip)*HS + tid, xn);
          ast(cG + ((parp^1)*LNUM + ip)*HS + tid, cn);
          if (ip == 3) out[tp*HS + tid] = xn;
        }
      }
      if (bid < 64) {
        float xv = (i == 0) ? x[t*HS + tid] : xn;
        sh_xin[tid] = xv;
        sh_h[tid]   = ald(hG + (par*LNUM + i)*HS + tid);
        if (bid == 0) ast(xing + tid, xv);
      } else if (bid == 64) { ast(Yg + tid, 0.f); }
      else if (bid == 65)   { ast(ctxg + tid, 0.f); ast(ctxg + HS + tid, 0.f); }
      else if (bid == 66)   {
        if (tid < 4) ast(deng + tid, 0.f);
        else if (tid == 4) ast(s1g, 0.f);
        else if (tid == 5) ast(s1g + 1, 0.f);
      }
      __syncthreads();
      if (bid < 64) {
        const int f = bid*8 + w;
        float acc = 0;
#pragma unroll
        for (int k = 0; k < 8; ++k) {
          int e = lane + 64*k;
          acc += pH1wx[k]*sh_xin[e] + pH1wh[k]*sh_h[e];
        }
        acc = wred(acc);
        if (lane == 0) ast(z1g + f, acc + bx[(i*3+1)*HS + f] + bh[(i*3+1)*HS + f]);
      }
    }
    barrier_pf(bflags, brel, gen, [&]{ pfH2(i); }); ++gen;
    // ---------- H2: t1 + deferred q accum + stats1 (bid<32); z gates 0,2 (bid>=128) ----------
    if (bid < 32) {
      sh_vec[tid] = sigm(ald(z1g + tid));  // f0
      __syncthreads();
      const int j0 = bid*16;
#pragma unroll
      for (int rr = 0; rr < 2; ++rr) {
        const int r = w + rr*8, j = j0 + r;
        float acc = 0;
#pragma unroll
        for (int k = 0; k < 8; ++k) acc += pH2wc[rr][k]*sh_vec[lane + 64*k];
        acc = wred(acc);
        if (lane == 0) {
          float t1v = sh_vec[j] + acc + csag[i*HS + j];
          sh_t1[r]  = t1v;   // persists in LDS until H4 (same block)
          sh_aux[r] = t1v;
        }
      }
      __syncthreads();
      {
        float yl = 0;
#pragma unroll
        for (int r = 0; r < 16; ++r) yl += sh_aux[r] * pH2wq[r];
        atomicAdd(&Yg[tid], yl);
      }
      if (w == 0 && lane < 16) {
        float v = sh_aux[lane], s_ = v, q_ = v*v;
#pragma unroll
        for (int m = 8; m; m >>= 1) { s_ += __shfl_xor(s_, m); q_ += __shfl_xor(q_, m); }
        if (lane == 0) { atomicAdd(&s1g[0], s_); atomicAdd(&s1g[1], q_); }
      }
    } else if (bid == 32) {
      ast(Y2g + tid, 0.f); ast(Y2g + HS + tid, 0.f);
      ast(Y2g + 2*HS + tid, 0.f); ast(Y2g + 3*HS + tid, 0.f);
      if (tid == 0) ast(s2g, 0.f);
      if (tid == 1) ast(s2g + 1, 0.f);
    } else if (bid >= 128) {
      sh_xin[tid] = ald(xing + tid);
      sh_h[tid]   = ald(hG + (par*LNUM + i)*HS + tid);
      __syncthreads();
      const int rowid = (bid-128)*8 + w;
      const int g = (rowid < 512) ? 0 : 2;
      const int f = rowid & 511;
      float acc = 0;
#pragma unroll
      for (int k = 0; k < 8; ++k) {
        int e = lane + 64*k;
        acc += pH2zx[k]*sh_xin[e] + pH2zh[k]*sh_h[e];
      }
      acc = wred(acc);
      if (lane == 0) ast(z02g + (g ? HS : 0) + f, acc + bx[(i*3+g)*HS + f] + bh[(i*3+g)*HS + f]);
    }
    barrier_pf(bflags, brel, gen, [&]{ pfH3(i); }); ++gen;
    // ---------- H3: attention scores + exp + ctx partials + denominator ----------
    {
      const int h = bid >> 6, mb = (bid & 63)*32;
      if (tid < 128) {
        float s10 = ald(s1g), s11 = ald(s1g + 1);
        float m1 = s10*INV512;
        float r1 = rsqrtf(s11*INV512 - m1*m1 + 1e-5f);
        int f = h*128 + tid;
        sh_q[tid] = r1*(ald(Yg + f) - m1*sqg[i*HS + f]) + cbqg[i*HS + f];
      }
      __syncthreads();
#pragma unroll
      for (int c = 0; c < 4; ++c) {
        float acc = sh_q[lane]*pH3k[c][0] + sh_q[lane+64]*pH3k[c][1];
        acc = wred(acc);
        if (lane == 0) sh_p[w*4 + c] = __expf(acc * QSCALE);
      }
      __syncthreads();
      if (w < 2) {
        float acc = 0;
#pragma unroll
        for (int ml = 0; ml < 16; ++ml) acc += sh_p[ml] * pH3v[ml];
        atomicAdd(&ctxg[h*128 + tid], acc);
      } else if (w == 4 || w == 5) {
        float acc = 0;
#pragma unroll
        for (int ml = 0; ml < 16; ++ml) acc += sh_p[16 + ml] * pH3v[ml];
        atomicAdd(&ctxg[HS + h*128 + (tid - 256)], acc);
      } else if (w == 6) {
        if (lane < 32) {
          float s_ = sh_p[lane];
#pragma unroll
          for (int m = 16; m; m >>= 1) s_ += __shfl_xor(s_, m);
          if (lane == 0) atomicAdd(&deng[h], s_);
        }
      }
    }
    barrier_pf(bflags, brel, gen, [&]{ pfH4(i); }); ++gen;
    // ---------- H4: t2 = x1 + caWo@(ctx/den) + bo; stats2 (bid<32) ----------
    if (bid < 32) {
      sh_vec[tid] = (ald(ctxg + tid) + ald(ctxg + HS + tid)) / ald(deng + (tid >> 7));
      __syncthreads();
      float s10 = ald(s1g), s11 = ald(s1g + 1);
      const float m1 = s10*INV512;
      const float r1 = rsqrtf(s11*INV512 - m1*m1 + 1e-5f);
      const int j0 = bid*16;
#pragma unroll
      for (int rr = 0; rr < 2; ++rr) {
        const int r = w + rr*8, j = j0 + r;
        float acc = 0;
#pragma unroll
        for (int k = 0; k < 8; ++k) acc += pH4ca[rr][k]*sh_vec[lane + 64*k];
        acc = wred(acc);
        if (lane == 0) {
          float x1j = (sh_t1[r]-m1)*r1*lnG[(i*3+0)*HS + j] + lnB[(i*3+0)*HS + j];
          float t2v = x1j + acc + caBo[i*HS + j];
          ast(t2g + j, t2v);
          sh_aux[r] = t2v;
        }
      }
      __syncthreads();
      if (w == 0 && lane < 16) {
        float v = sh_aux[lane], s_ = v, q_ = v*v;
#pragma unroll
        for (int m = 8; m; m >>= 1) { s_ += __shfl_xor(s_, m); q_ += __shfl_xor(q_, m); }
        if (lane == 0) { atomicAdd(&s2g[0], s_); atomicAdd(&s2g[1], q_); }
      }
    }
    barrier_pf(bflags, brel, gen, [&]{ pfH5(i); }); ++gen;
    // ---------- H5: ff1 = relu(W1@x2+b1); Y2[plane] += W2T[:,chunk]@ff1[chunk] ----------
    {
      float s20 = ald(s2g), s21 = ald(s2g + 1);
      const float m2 = s20*INV512;
      const float r2 = rsqrtf(s21*INV512 - m2*m2 + 1e-5f);
      sh_vec[tid] = (ald(t2g + tid)-m2)*r2*lnG[(i*3+1)*HS + tid] + lnB[(i*3+1)*HS + tid];
      __syncthreads();
      const int kk = bid*8 + w;
      float acc = 0;
#pragma unroll
      for (int k = 0; k < 8; ++k) acc += pH5f1[k]*sh_vec[lane + 64*k];
      acc = wred(acc);
      if (lane == 0) sh_aux[w] = fmaxf(acc + ffB1[i*FFD + kk], 0.f);
      __syncthreads();
      float yl = 0;
#pragma unroll
      for (int r = 0; r < 8; ++r) yl += sh_aux[r] * pH5w2[r];
      atomicAdd(&Y2g[(bid >> 6)*HS + tid], yl);
    }
    barrier_pf(bflags, brel, gen, [&]{ pfH1((s+1) & 3); }); ++gen;
  }

  // ---------- final: update for (t=127, i=3) + output assembly ----------
  if (bid == 0) {
    float xn, cn;
    do_update(3, 1, tid, t2g, s2g, Y2g, z02g, cG, lnG, lnB, ffB2, sh_red, w, lane, xn, cn);
    out[127*HS + tid] = xn;
    out[TT*HS + 3*HS + tid] = xn;                 // h_T[3]
    out[TT*HS + LNUM*HS + 3*HS + tid] = cn;       // c_T[3]
#pragma unroll
    for (int ii = 0; ii < 3; ++ii) {
      out[TT*HS + ii*HS + tid]            = ald(hG + (0*LNUM + ii)*HS + tid);
      out[TT*HS + LNUM*HS + ii*HS + tid]  = ald(cG + (0*LNUM + ii)*HS + tid);
    }
  }
}

// ---------------- host launcher ----------------
extern "C" void kernel_launch(void* const* d_in, const int* in_sizes, int n_in,
                              void* d_out, int out_size, void* d_ws, size_t ws_size,
                              hipStream_t stream) {
  const float* x      = (const float*)d_in[0];
  const float* hist   = (const float*)d_in[1];
  const float* Wx     = (const float*)d_in[2];
  const float* bx     = (const float*)d_in[3];
  const float* Wh     = (const float*)d_in[4];
  const float* bh     = (const float*)d_in[5];
  const float* saWin  = (const float*)d_in[6];
  const float* saBin  = (const float*)d_in[7];
  const float* saWo   = (const float*)d_in[8];
  const float* saBo   = (const float*)d_in[9];
  const float* caWin  = (const float*)d_in[10];
  const float* caBin  = (const float*)d_in[11];
  const float* caWo   = (const float*)d_in[12];
  const float* caBo   = (const float*)d_in[13];
  const float* ffW1   = (const float*)d_in[14];
  const float* ffB1   = (const float*)d_in[15];
  const float* ffW2   = (const float*)d_in[16];
  const float* ffB2   = (const float*)d_in[17];
  const float* lnG    = (const float*)d_in[18];
  const float* lnB    = (const float*)d_in[19];
  float* ws  = (float*)d_ws;
  float* out = (float*)d_out;

  hipMemsetAsync((char*)d_ws + OFF_STATE*sizeof(float), 0,
                 (WS_TOTAL - OFF_STATE)*sizeof(float), stream);

  kv_gemm<<<dim3(MMEM/64, HS/64, LNUM), 256, 0, stream>>>(hist, caWin, caBin, ws + OFF_K, HS);
  kv_gemm<<<dim3(MMEM/64, HS/64, LNUM), 256, 0, stream>>>(hist, caWin, caBin, ws + OFF_V, 2*HS);
  wcomb_gemm<<<dim3(HS/64, HS/64, LNUM), 256, 0, stream>>>(saWo, saWin, ws + OFF_WCOMB);
  csa_kernel<<<(LNUM*HS)/4, 256, 0, stream>>>(saWo, saBin, saBo, ws + OFF_CSA);
  transpose_scale<<<dim3(HS/32, HS/32, LNUM), 256, 0, stream>>>(
      caWin, (size_t)(3*HS)*HS, HS, HS, lnG, (size_t)(3*HS), ws + OFF_WQT, (size_t)HS*HS);
  sqcbq_kernel<<<(LNUM*HS)/4, 256, 0, stream>>>(caWin, caBin, lnG, lnB, ws + OFF_SQ, ws + OFF_CBQ);
  transpose_scale<<<dim3(FFD/32, HS/32, LNUM), 256, 0, stream>>>(
      ffW2, (size_t)HS*FFD, HS, FFD, nullptr, 0, ws + OFF_W2T, (size_t)FFD*HS);

  seq_kernel<<<NB, NT, 0, stream>>>(x, Wx, bx, Wh, bh, caWo, caBo,
                                    ffW1, ffB1, ffB2, lnG, lnB, ws, out);
}